// Round 1
// baseline (296.944 us; speedup 1.0000x reference)
//
#include <hip/hip_runtime.h>
#include <hip/hip_bf16.h>
#include <stdint.h>

typedef __attribute__((ext_vector_type(8))) short v8s;
typedef __attribute__((ext_vector_type(8))) __bf16 bf16x8;
typedef __attribute__((ext_vector_type(4))) float v4f;

__device__ __forceinline__ unsigned short f2bf(float f) {
  unsigned int u = __float_as_uint(f);
  u += 0x7fff + ((u >> 16) & 1);
  return (unsigned short)(u >> 16);
}
__device__ __forceinline__ float bf2f(unsigned short h) {
  return __uint_as_float(((unsigned int)h) << 16);
}

// ---------------- cast f32 -> bf16 ----------------
__global__ void cast_f32_bf16(const float* __restrict__ s, unsigned short* __restrict__ d, int n) {
  int i = (blockIdx.x * blockDim.x + threadIdx.x) * 4;
  if (i >= n) return;
  float4 v = *(const float4*)(s + i);
  ushort4 o;
  o.x = f2bf(v.x); o.y = f2bf(v.y); o.z = f2bf(v.z); o.w = f2bf(v.w);
  *(ushort4*)(d + i) = o;
}

// ---------------- GEMM: C[M,N] = A[M,K] * B[N,K]^T + bias ----------------
#define BM 128
#define BN 128
#define BK 64

__device__ __forceinline__ void gload_lds16(const void* g, void* l) {
  __builtin_amdgcn_global_load_lds(
      (const __attribute__((address_space(1))) void*)g,
      (__attribute__((address_space(3))) void*)l,
      16, 0, 0);
}

template <int OUT_BF16>
__global__ __launch_bounds__(256, 2) void gemm_bt(
    const unsigned short* __restrict__ A,  // M x K bf16
    const unsigned short* __restrict__ B,  // N x K bf16
    const float* __restrict__ bias,        // N
    void* __restrict__ C,
    int M, int N, int K)
{
  __shared__ __align__(16) unsigned short As[BM * BK];
  __shared__ __align__(16) unsigned short Bs[BN * BK];

  const int tid  = threadIdx.x;
  const int lane = tid & 63;
  const int wid  = tid >> 6;            // 0..3
  const int wr   = wid >> 1, wc = wid & 1;

  const int tm = blockIdx.y * BM;
  const int tn = blockIdx.x * BN;

  // staging geometry: per 1KB wave-issue: 8 rows x 8 chunks(16B)
  const int srow = lane >> 3;           // row within 8-row group (== row&7)
  const int scb  = lane & 7;            // physical chunk this lane fills
  const int scl  = scb ^ srow;          // logical (k) chunk to fetch (XOR swizzle, involution)
  const int gco  = scl * 8;             // element offset within 64-col tile row

  v4f acc[4][4];
#pragma unroll
  for (int m = 0; m < 4; ++m)
#pragma unroll
    for (int n = 0; n < 4; ++n)
      acc[m][n] = (v4f){0.f, 0.f, 0.f, 0.f};

  const unsigned short* Ab = A + (size_t)tm * K;
  const unsigned short* Bb = B + (size_t)tn * K;
  const int kTiles = K / BK;

  for (int kt = 0; kt < kTiles; ++kt) {
    const int k0 = kt * BK;
#pragma unroll
    for (int i = 0; i < 4; ++i) {
      const int r0 = wid * 32 + i * 8;
      gload_lds16(Ab + (size_t)(r0 + srow) * K + k0 + gco, &As[r0 * BK]);
    }
#pragma unroll
    for (int i = 0; i < 4; ++i) {
      const int r0 = wid * 32 + i * 8;
      gload_lds16(Bb + (size_t)(r0 + srow) * K + k0 + gco, &Bs[r0 * BK]);
    }
    __syncthreads();

#pragma unroll
    for (int ks = 0; ks < 2; ++ks) {
      bf16x8 av[4], bv[4];
#pragma unroll
      for (int m = 0; m < 4; ++m) {
        const int row  = wr * 64 + m * 16 + (lane & 15);
        const int cl   = ks * 4 + (lane >> 4);
        const int phys = cl ^ (row & 7);
        av[m] = *(const bf16x8*)&As[row * BK + phys * 8];
      }
#pragma unroll
      for (int n = 0; n < 4; ++n) {
        const int row  = wc * 64 + n * 16 + (lane & 15);
        const int cl   = ks * 4 + (lane >> 4);
        const int phys = cl ^ (row & 7);
        bv[n] = *(const bf16x8*)&Bs[row * BK + phys * 8];
      }
#pragma unroll
      for (int m = 0; m < 4; ++m)
#pragma unroll
        for (int n = 0; n < 4; ++n)
          acc[m][n] = __builtin_amdgcn_mfma_f32_16x16x32_bf16(av[m], bv[n], acc[m][n], 0, 0, 0);
    }
    __syncthreads();
  }

  // epilogue: D row=(lane>>4)*4+r, col=lane&15 within each 16x16 fragment
  const int cr0 = tm + wr * 64 + (lane >> 4) * 4;
  const int cc0 = tn + wc * 64 + (lane & 15);
#pragma unroll
  for (int n = 0; n < 4; ++n) {
    const int col = cc0 + n * 16;
    const float bz = bias[col];
#pragma unroll
    for (int m = 0; m < 4; ++m) {
      const int row = cr0 + m * 16;
#pragma unroll
      for (int r = 0; r < 4; ++r) {
        const float val = acc[m][n][r] + bz;
        if (OUT_BF16)
          ((unsigned short*)C)[(size_t)(row + r) * N + col] = f2bf(val);
        else
          ((float*)C)[(size_t)(row + r) * N + col] = val;
      }
    }
  }
}

// ---------------- RMSNorm (+ channel-shift mix for Q), in place ----------------
__global__ __launch_bounds__(256) void rmsnorm_mix(
    unsigned short* __restrict__ Qb, unsigned short* __restrict__ Kb,
    const float* __restrict__ gq, const float* __restrict__ gk,
    const float* __restrict__ wmix)
{
  const int row = blockIdx.x;            // b*L + l
  const bool isQ = (blockIdx.y == 0);
  unsigned short* base = (isQ ? Qb : Kb) + (size_t)row * 2048;
  const float* g = isQ ? gq : gk;

  __shared__ float sv[2048];
  __shared__ float red[4];

  const int t = threadIdx.x;
  v8s raw = *(const v8s*)(base + t * 8);
  float x[8];
  float ss = 0.f;
#pragma unroll
  for (int j = 0; j < 8; ++j) { x[j] = bf2f((unsigned short)raw[j]); ss += x[j] * x[j]; }
#pragma unroll
  for (int o = 32; o > 0; o >>= 1) ss += __shfl_xor(ss, o, 64);
  if ((t & 63) == 0) red[t >> 6] = ss;
  __syncthreads();
  const float tot = red[0] + red[1] + red[2] + red[3];
  const float inv = rsqrtf(tot * (1.0f / 2048.0f) + 1e-6f);

  if (isQ) {
#pragma unroll
    for (int j = 0; j < 8; ++j) sv[t * 8 + j] = x[j] * inv * g[t * 8 + j];
    __syncthreads();
    const float scale = 0.08838834764831845f;  // 1/sqrt(128)
    const float w0 = wmix[0], w1 = wmix[1], w2 = wmix[2], w3 = wmix[3], w4 = wmix[4];
    v8s ov;
#pragma unroll
    for (int j = 0; j < 8; ++j) {
      const int idx = t * 8 + j;
      const int hb = idx & ~127;
      const int d  = idx & 127;
      float a = w0 * sv[hb + d]
              + w1 * sv[hb + ((d - 1) & 127)]
              + w2 * sv[hb + ((d - 2) & 127)]
              + w3 * sv[hb + ((d - 4) & 127)]
              + w4 * sv[hb + ((d - 8) & 127)];
      ov[j] = (short)f2bf(a * scale);
    }
    *(v8s*)(base + t * 8) = ov;
  } else {
    v8s ov;
#pragma unroll
    for (int j = 0; j < 8; ++j) ov[j] = (short)f2bf(x[j] * inv * g[t * 8 + j]);
    *(v8s*)(base + t * 8) = ov;
  }
}

// ---------------- attention over 16 fixed sequence shifts ----------------
__global__ __launch_bounds__(256) void attention_k(
    const unsigned short* __restrict__ Qm,
    const unsigned short* __restrict__ Kn,
    const unsigned short* __restrict__ Vb,
    unsigned short* __restrict__ AO)
{
  const int blk = blockIdx.x;            // b*2048 + l
  const int l = blk & 2047;
  const int t = threadIdx.x;

  __shared__ __align__(16) unsigned short sq[2048];
  __shared__ float sp[16][17];

  const size_t rowbase = (size_t)blk * 2048;
  *(v8s*)&sq[t * 8] = *(const v8s*)(Qm + rowbase + t * 8);
  __syncthreads();

  const int SH[16] = {0, 1, -1, 3, -3, 7, -7, 20, -20, 53, -53, 141, -141, 380, -380, 1024};
  const int h = t >> 4, s = t & 15;
  const int ls = (l - SH[s]) & 2047;
  const size_t krow = (size_t)((blk & ~2047) + ls) * 2048 + h * 128;

  float dot = 0.f;
#pragma unroll
  for (int i = 0; i < 16; ++i) {
    v8s kv = *(const v8s*)(Kn + krow + i * 8);
    v8s qv = *(const v8s*)&sq[h * 128 + i * 8];
#pragma unroll
    for (int j = 0; j < 8; ++j)
      dot += bf2f((unsigned short)kv[j]) * bf2f((unsigned short)qv[j]);
  }
  float mx = dot;
#pragma unroll
  for (int o = 8; o > 0; o >>= 1) mx = fmaxf(mx, __shfl_xor(mx, o, 16));
  const float e = __expf(dot - mx);
  float sum = e;
#pragma unroll
  for (int o = 8; o > 0; o >>= 1) sum += __shfl_xor(sum, o, 16);
  sp[h][s] = e / sum;
  __syncthreads();

  const int d0 = (t & 15) * 8;
  float o8[8] = {0, 0, 0, 0, 0, 0, 0, 0};
#pragma unroll
  for (int si = 0; si < 16; ++si) {
    const float p = sp[h][si];
    const int ls2 = (l - SH[si]) & 2047;
    const size_t vrow = (size_t)((blk & ~2047) + ls2) * 2048 + h * 128 + d0;
    v8s vv = *(const v8s*)(Vb + vrow);
#pragma unroll
    for (int j = 0; j < 8; ++j) o8[j] += p * bf2f((unsigned short)vv[j]);
  }
  v8s ov;
#pragma unroll
  for (int j = 0; j < 8; ++j) ov[j] = (short)f2bf(o8[j]);
  *(v8s*)(AO + rowbase + h * 128 + d0) = ov;
}

// ---------------- launch ----------------
extern "C" void kernel_launch(void* const* d_in, const int* in_sizes, int n_in,
                              void* d_out, int out_size, void* d_ws, size_t ws_size,
                              hipStream_t stream) {
  const float* x    = (const float*)d_in[0];
  const float* wq   = (const float*)d_in[1];
  const float* bq   = (const float*)d_in[2];
  const float* wk   = (const float*)d_in[3];
  const float* bk   = (const float*)d_in[4];
  const float* wv   = (const float*)d_in[5];
  const float* bv   = (const float*)d_in[6];
  const float* gq   = (const float*)d_in[7];
  const float* gk   = (const float*)d_in[8];
  const float* wmix = (const float*)d_in[9];
  const float* wo   = (const float*)d_in[10];
  const float* bo   = (const float*)d_in[11];

  const int M = 4096;      // B*L
  const int K = 2048;      // QUERY_DIM
  const int N = 2048;      // INNER

  size_t off = 0;
  auto alloc = [&](size_t bytes) -> void* {
    void* p = (char*)d_ws + off;
    off += (bytes + 255) & ~(size_t)255;
    return p;
  };
  unsigned short* xb  = (unsigned short*)alloc((size_t)M * K * 2);
  unsigned short* wqb = (unsigned short*)alloc((size_t)N * K * 2);
  unsigned short* wkb = (unsigned short*)alloc((size_t)N * K * 2);
  unsigned short* wvb = (unsigned short*)alloc((size_t)N * K * 2);
  unsigned short* wob = (unsigned short*)alloc((size_t)N * K * 2);
  unsigned short* Qb  = (unsigned short*)alloc((size_t)M * N * 2);
  unsigned short* Kb  = (unsigned short*)alloc((size_t)M * N * 2);
  unsigned short* Vb  = (unsigned short*)alloc((size_t)M * N * 2);
  unsigned short* AOb = (unsigned short*)alloc((size_t)M * N * 2);

  cast_f32_bf16<<<(M * K) / 1024, 256, 0, stream>>>(x, xb, M * K);
  cast_f32_bf16<<<(N * K) / 1024, 256, 0, stream>>>(wq, wqb, N * K);
  cast_f32_bf16<<<(N * K) / 1024, 256, 0, stream>>>(wk, wkb, N * K);
  cast_f32_bf16<<<(N * K) / 1024, 256, 0, stream>>>(wv, wvb, N * K);
  cast_f32_bf16<<<(N * K) / 1024, 256, 0, stream>>>(wo, wob, N * K);

  dim3 gg(N / BN, M / BM);
  gemm_bt<1><<<gg, 256, 0, stream>>>(xb, wqb, bq, Qb, M, N, K);
  gemm_bt<1><<<gg, 256, 0, stream>>>(xb, wkb, bk, Kb, M, N, K);
  gemm_bt<1><<<gg, 256, 0, stream>>>(xb, wvb, bv, Vb, M, N, K);

  rmsnorm_mix<<<dim3(M, 2), 256, 0, stream>>>(Qb, Kb, gq, gk, wmix);
  attention_k<<<M, 256, 0, stream>>>(Qb, Kb, Vb, AOb);

  gemm_bt<0><<<gg, 256, 0, stream>>>(AOb, wob, bo, d_out, M, N, K);
}

// Round 2
// 282.297 us; speedup vs baseline: 1.0519x; 1.0519x over previous
//
#include <hip/hip_runtime.h>
#include <hip/hip_bf16.h>
#include <stdint.h>

typedef __attribute__((ext_vector_type(8))) short v8s;
typedef __attribute__((ext_vector_type(8))) __bf16 bf16x8;
typedef __attribute__((ext_vector_type(4))) float v4f;

__device__ __forceinline__ unsigned short f2bf(float f) {
  unsigned int u = __float_as_uint(f);
  u += 0x7fff + ((u >> 16) & 1);
  return (unsigned short)(u >> 16);
}
__device__ __forceinline__ float bf2f(unsigned short h) {
  return __uint_as_float(((unsigned int)h) << 16);
}

// ---------------- cast f32 -> bf16 ----------------
__global__ void cast_f32_bf16(const float* __restrict__ s, unsigned short* __restrict__ d, int n) {
  int i = (blockIdx.x * blockDim.x + threadIdx.x) * 4;
  if (i >= n) return;
  float4 v = *(const float4*)(s + i);
  ushort4 o;
  o.x = f2bf(v.x); o.y = f2bf(v.y); o.z = f2bf(v.z); o.w = f2bf(v.w);
  *(ushort4*)(d + i) = o;
}

// ---------------- GEMM: C[M,N] = A[M,K] * B[N,K]^T + bias ----------------
// OUT_MODE: 0 = f32 row-major, 1 = bf16 row-major, 2 = bf16 transposed to [b,h,l,d]
#define BM 128
#define BN 128
#define BK 64

__device__ __forceinline__ void gload_lds16(const void* g, void* l) {
  __builtin_amdgcn_global_load_lds(
      (const __attribute__((address_space(1))) void*)g,
      (__attribute__((address_space(3))) void*)l,
      16, 0, 0);
}

template <int OUT_MODE>
__global__ __launch_bounds__(256, 2) void gemm_bt(
    const unsigned short* __restrict__ A,  // M x K bf16
    const unsigned short* __restrict__ B,  // N x K bf16
    const float* __restrict__ bias,        // N
    void* __restrict__ C,
    int M, int N, int K)
{
  __shared__ __align__(16) unsigned short As[BM * BK];
  __shared__ __align__(16) unsigned short Bs[BN * BK];

  const int tid  = threadIdx.x;
  const int lane = tid & 63;
  const int wid  = tid >> 6;            // 0..3
  const int wr   = wid >> 1, wc = wid & 1;

  const int tm = blockIdx.y * BM;
  const int tn = blockIdx.x * BN;

  // staging geometry: per 1KB wave-issue: 8 rows x 8 chunks(16B)
  const int srow = lane >> 3;           // row within 8-row group (== row&7)
  const int scb  = lane & 7;            // physical chunk this lane fills
  const int scl  = scb ^ srow;          // logical (k) chunk to fetch (XOR swizzle, involution)
  const int gco  = scl * 8;             // element offset within 64-col tile row

  v4f acc[4][4];
#pragma unroll
  for (int m = 0; m < 4; ++m)
#pragma unroll
    for (int n = 0; n < 4; ++n)
      acc[m][n] = (v4f){0.f, 0.f, 0.f, 0.f};

  const unsigned short* Ab = A + (size_t)tm * K;
  const unsigned short* Bb = B + (size_t)tn * K;
  const int kTiles = K / BK;

  for (int kt = 0; kt < kTiles; ++kt) {
    const int k0 = kt * BK;
#pragma unroll
    for (int i = 0; i < 4; ++i) {
      const int r0 = wid * 32 + i * 8;
      gload_lds16(Ab + (size_t)(r0 + srow) * K + k0 + gco, &As[r0 * BK]);
    }
#pragma unroll
    for (int i = 0; i < 4; ++i) {
      const int r0 = wid * 32 + i * 8;
      gload_lds16(Bb + (size_t)(r0 + srow) * K + k0 + gco, &Bs[r0 * BK]);
    }
    __syncthreads();

#pragma unroll
    for (int ks = 0; ks < 2; ++ks) {
      bf16x8 av[4], bv[4];
#pragma unroll
      for (int m = 0; m < 4; ++m) {
        const int row  = wr * 64 + m * 16 + (lane & 15);
        const int cl   = ks * 4 + (lane >> 4);
        const int phys = cl ^ (row & 7);
        av[m] = *(const bf16x8*)&As[row * BK + phys * 8];
      }
#pragma unroll
      for (int n = 0; n < 4; ++n) {
        const int row  = wc * 64 + n * 16 + (lane & 15);
        const int cl   = ks * 4 + (lane >> 4);
        const int phys = cl ^ (row & 7);
        bv[n] = *(const bf16x8*)&Bs[row * BK + phys * 8];
      }
#pragma unroll
      for (int m = 0; m < 4; ++m)
#pragma unroll
        for (int n = 0; n < 4; ++n)
          acc[m][n] = __builtin_amdgcn_mfma_f32_16x16x32_bf16(av[m], bv[n], acc[m][n], 0, 0, 0);
    }
    __syncthreads();
  }

  // epilogue: D row=(lane>>4)*4+r, col=lane&15 within each 16x16 fragment
  const int cr0 = tm + wr * 64 + (lane >> 4) * 4;
  const int cc0 = tn + wc * 64 + (lane & 15);
#pragma unroll
  for (int n = 0; n < 4; ++n) {
    const int col = cc0 + n * 16;
    const float bz = bias[col];
#pragma unroll
    for (int m = 0; m < 4; ++m) {
      const int row = cr0 + m * 16;
#pragma unroll
      for (int r = 0; r < 4; ++r) {
        const float val = acc[m][n][r] + bz;
        const int rr = row + r;
        if (OUT_MODE == 0) {
          ((float*)C)[(size_t)rr * N + col] = val;
        } else if (OUT_MODE == 1) {
          ((unsigned short*)C)[(size_t)rr * N + col] = f2bf(val);
        } else {
          // transposed store: [b,h,l,d]
          const int bb = rr >> 11, ll = rr & 2047;
          const int hh = col >> 7, dd = col & 127;
          ((unsigned short*)C)[(((size_t)(bb * 16 + hh)) * 2048 + ll) * 128 + dd] = f2bf(val);
        }
      }
    }
  }
}

// ---------------- RMSNorm (+ channel-shift mix for Q), writes transposed [b,h,l,d] ----------------
__global__ __launch_bounds__(256) void rmsnorm_mix(
    const unsigned short* __restrict__ Qb, const unsigned short* __restrict__ Kb,
    unsigned short* __restrict__ Qt, unsigned short* __restrict__ Kt,
    const float* __restrict__ gq, const float* __restrict__ gk,
    const float* __restrict__ wmix)
{
  const int row = blockIdx.x;            // b*L + l
  const bool isQ = (blockIdx.y == 0);
  const unsigned short* src = (isQ ? Qb : Kb) + (size_t)row * 2048;
  unsigned short* dstbase = isQ ? Qt : Kt;
  const float* g = isQ ? gq : gk;
  const int b = row >> 11, l = row & 2047;

  __shared__ float sv[2048];
  __shared__ float red[4];

  const int t = threadIdx.x;
  v8s raw = *(const v8s*)(src + t * 8);
  float x[8];
  float ss = 0.f;
#pragma unroll
  for (int j = 0; j < 8; ++j) { x[j] = bf2f((unsigned short)raw[j]); ss += x[j] * x[j]; }
#pragma unroll
  for (int o = 32; o > 0; o >>= 1) ss += __shfl_xor(ss, o, 64);
  if ((t & 63) == 0) red[t >> 6] = ss;
  __syncthreads();
  const float tot = red[0] + red[1] + red[2] + red[3];
  const float inv = rsqrtf(tot * (1.0f / 2048.0f) + 1e-6f);

  const int h = t >> 4;
  unsigned short* dst = dstbase + (((size_t)(b * 16 + h)) * 2048 + l) * 128 + ((t * 8) & 127);

  if (isQ) {
#pragma unroll
    for (int j = 0; j < 8; ++j) sv[t * 8 + j] = x[j] * inv * g[t * 8 + j];
    __syncthreads();
    const float scale = 0.08838834764831845f;  // 1/sqrt(128)
    const float w0 = wmix[0], w1 = wmix[1], w2 = wmix[2], w3 = wmix[3], w4 = wmix[4];
    v8s ov;
#pragma unroll
    for (int j = 0; j < 8; ++j) {
      const int idx = t * 8 + j;
      const int hb = idx & ~127;
      const int d  = idx & 127;
      float a = w0 * sv[hb + d]
              + w1 * sv[hb + ((d - 1) & 127)]
              + w2 * sv[hb + ((d - 2) & 127)]
              + w3 * sv[hb + ((d - 4) & 127)]
              + w4 * sv[hb + ((d - 8) & 127)];
      ov[j] = (short)f2bf(a * scale);
    }
    *(v8s*)dst = ov;
  } else {
    v8s ov;
#pragma unroll
    for (int j = 0; j < 8; ++j) ov[j] = (short)f2bf(x[j] * inv * g[t * 8 + j]);
    *(v8s*)dst = ov;
  }
}

// ---------------- attention over 16 fixed sequence shifts (head-major) ----------------
__global__ __launch_bounds__(256) void attention_k(
    const unsigned short* __restrict__ Qt,
    const unsigned short* __restrict__ Kt,
    const unsigned short* __restrict__ Vt,
    unsigned short* __restrict__ AO)
{
  const int bid = blockIdx.x;            // (b,h,lc)
  const int b  = bid >> 9;
  const int h  = (bid >> 5) & 15;
  const int lc = bid & 31;
  const int l0 = lc * 64;

  const int t = threadIdx.x;
  const int l = t >> 2;                  // 0..63
  const int q = t & 3;                   // dim quarter (32 elems)

  __shared__ float sc[64][17];

  const size_t plane = ((size_t)(b * 16 + h)) * 2048 * 128;
  const int myl = l0 + l;

  // Q slice in registers (already mixed + scaled)
  v8s qv[4];
  {
    const unsigned short* qp = Qt + plane + (size_t)myl * 128 + q * 32;
#pragma unroll
    for (int i = 0; i < 4; ++i) qv[i] = *(const v8s*)(qp + i * 8);
  }

  const int SH[16] = {0, 1, -1, 3, -3, 7, -7, 20, -20, 53, -53, 141, -141, 380, -380, 1024};

  // pass 1: scores
#pragma unroll 4
  for (int s = 0; s < 16; ++s) {
    const int row = (myl - SH[s]) & 2047;
    const unsigned short* kp = Kt + plane + (size_t)row * 128 + q * 32;
    float dot = 0.f;
#pragma unroll
    for (int i = 0; i < 4; ++i) {
      v8s kv = *(const v8s*)(kp + i * 8);
#pragma unroll
      for (int j = 0; j < 8; ++j)
        dot += bf2f((unsigned short)kv[j]) * bf2f((unsigned short)qv[i][j]);
    }
    dot += __shfl_xor(dot, 1, 64);
    dot += __shfl_xor(dot, 2, 64);
    if (q == 0) sc[l][s] = dot;
  }
  __syncthreads();

  // softmax over s (each lane reads all 16, writes its 4)
  {
    float v0[16];
#pragma unroll
    for (int s = 0; s < 16; ++s) v0[s] = sc[l][s];
    float mx = v0[0];
#pragma unroll
    for (int s = 1; s < 16; ++s) mx = fmaxf(mx, v0[s]);
    float sum = 0.f;
    float e[4];
#pragma unroll
    for (int s = 0; s < 16; ++s) {
      const float ee = __expf(v0[s] - mx);
      sum += ee;
      if ((s >> 2) == q) e[s & 3] = ee;
    }
    const float inv = 1.f / sum;
#pragma unroll
    for (int i = 0; i < 4; ++i) sc[l][q * 4 + i] = e[i] * inv;
  }
  __syncthreads();

  // pass 2: output accumulate
  float o[32];
#pragma unroll
  for (int i = 0; i < 32; ++i) o[i] = 0.f;
#pragma unroll 2
  for (int s = 0; s < 16; ++s) {
    const float p = sc[l][s];
    const int row = (myl - SH[s]) & 2047;
    const unsigned short* vp = Vt + plane + (size_t)row * 128 + q * 32;
#pragma unroll
    for (int i = 0; i < 4; ++i) {
      v8s vv = *(const v8s*)(vp + i * 8);
#pragma unroll
      for (int j = 0; j < 8; ++j)
        o[i * 8 + j] += p * bf2f((unsigned short)vv[j]);
    }
  }

  unsigned short* op = AO + ((size_t)(b * 2048 + myl)) * 2048 + h * 128 + q * 32;
#pragma unroll
  for (int i = 0; i < 4; ++i) {
    v8s ov;
#pragma unroll
    for (int j = 0; j < 8; ++j) ov[j] = (short)f2bf(o[i * 8 + j]);
    *(v8s*)(op + i * 8) = ov;
  }
}

// ---------------- launch ----------------
extern "C" void kernel_launch(void* const* d_in, const int* in_sizes, int n_in,
                              void* d_out, int out_size, void* d_ws, size_t ws_size,
                              hipStream_t stream) {
  const float* x    = (const float*)d_in[0];
  const float* wq   = (const float*)d_in[1];
  const float* bq   = (const float*)d_in[2];
  const float* wk   = (const float*)d_in[3];
  const float* bk   = (const float*)d_in[4];
  const float* wv   = (const float*)d_in[5];
  const float* bv   = (const float*)d_in[6];
  const float* gq   = (const float*)d_in[7];
  const float* gk   = (const float*)d_in[8];
  const float* wmix = (const float*)d_in[9];
  const float* wo   = (const float*)d_in[10];
  const float* bo   = (const float*)d_in[11];

  const int M = 4096;      // B*L
  const int K = 2048;      // QUERY_DIM
  const int N = 2048;      // INNER
  const size_t MB = 1024 * 1024;

  char* ws = (char*)d_ws;
  // workspace plan (104 MB total, aliased):
  unsigned short* xb  = (unsigned short*)(ws + 0 * MB);    // 16MB; dead after gemmV
  unsigned short* Ktr = (unsigned short*)(ws + 0 * MB);    // alias of xb (written by rmsnorm, after gemms)
  unsigned short* wqb = (unsigned short*)(ws + 16 * MB);   // 8MB; dead after gemmQ
  unsigned short* wob = (unsigned short*)(ws + 16 * MB);   // alias of wqb (cast after gemmQ)
  unsigned short* wkb = (unsigned short*)(ws + 24 * MB);   // 8MB
  unsigned short* wvb = (unsigned short*)(ws + 32 * MB);   // 8MB
  unsigned short* Qb  = (unsigned short*)(ws + 40 * MB);   // 16MB; dead after rmsnorm
  unsigned short* AOb = (unsigned short*)(ws + 40 * MB);   // alias of Qb (attention out)
  unsigned short* Kb  = (unsigned short*)(ws + 56 * MB);   // 16MB
  unsigned short* Vt  = (unsigned short*)(ws + 72 * MB);   // 16MB (transposed V from gemm)
  unsigned short* Qtr = (unsigned short*)(ws + 88 * MB);   // 16MB

  cast_f32_bf16<<<(M * K) / 1024, 256, 0, stream>>>(x, xb, M * K);
  cast_f32_bf16<<<(N * K) / 1024, 256, 0, stream>>>(wq, wqb, N * K);
  cast_f32_bf16<<<(N * K) / 1024, 256, 0, stream>>>(wk, wkb, N * K);
  cast_f32_bf16<<<(N * K) / 1024, 256, 0, stream>>>(wv, wvb, N * K);

  dim3 gg(N / BN, M / BM);
  gemm_bt<1><<<gg, 256, 0, stream>>>(xb, wqb, bq, Qb, M, N, K);
  cast_f32_bf16<<<(N * K) / 1024, 256, 0, stream>>>(wo, wob, N * K);  // into wqb slot
  gemm_bt<1><<<gg, 256, 0, stream>>>(xb, wkb, bk, Kb, M, N, K);
  gemm_bt<2><<<gg, 256, 0, stream>>>(xb, wvb, bv, Vt, M, N, K);

  rmsnorm_mix<<<dim3(M, 2), 256, 0, stream>>>(Qb, Kb, Qtr, Ktr, gq, gk, wmix);
  attention_k<<<1024, 256, 0, stream>>>(Qtr, Ktr, Vt, AOb);

  gemm_bt<0><<<gg, 256, 0, stream>>>(AOb, wob, bo, d_out, M, N, K);
}